// Round 12
// baseline (91.272 us; speedup 1.0000x reference)
//
#include <hip/hip_runtime.h>

typedef unsigned short u16;
typedef unsigned int u32;
typedef __bf16 bf16x8 __attribute__((ext_vector_type(8)));
typedef float f32x4 __attribute__((ext_vector_type(4)));

// Prepped-weight layout in g_wbuf (bytes), rewritten fully by prep_kernel
// every launch (deterministic):
//   W1f @ 0      : 7 slices x 10240 B (slice kt = 10 frags x 1KB)   [71680]
//   W2f @ 71680  : 5 slices x 7168 B  (slice kt = 7 frags x 1KB)    [35840]
//   b1p @ 107520 : 160 f32 (zero-padded)
//   b2p @ 108160 : 112 f32 (zero-padded)
#define W2F_OFF 71680
#define B1_OFF 107520
#define B2_OFF 108160
#define WS_BYTES 108608

__device__ __align__(256) unsigned char g_wbuf[WS_BYTES];

__device__ __forceinline__ u16 f2bf(float f) {
  __bf16 b = (__bf16)f;                    // hw RNE convert
  return __builtin_bit_cast(u16, b);
}
__device__ __forceinline__ u32 pk2bf(float a, float b) {
  return (u32)f2bf(a) | ((u32)f2bf(b) << 16);  // fuses to v_cvt_pk_bf16_f32
}

typedef __attribute__((address_space(1))) const u32 gas_u32;
typedef __attribute__((address_space(3))) u32 las_u32;
// async global->LDS, 16B per lane: LDS dest = uniform base + lane*16
__device__ __forceinline__ void gl16(const void* g, void* l) {
  __builtin_amdgcn_global_load_lds((gas_u32*)g, (las_u32*)l, 16, 0, 0);
}

__global__ void prep_kernel(const float* __restrict__ W1, const float* __restrict__ b1,
                            const float* __restrict__ W2, const float* __restrict__ b2)
{
  const int stride = gridDim.x * blockDim.x;
  const int tid0 = blockIdx.x * blockDim.x + threadIdx.x;
  u16* w1f = (u16*)g_wbuf;
  for (int e = tid0; e < 35840; e += stride) {
    int j = e & 7, l = (e >> 3) & 63, nt = (e >> 9) % 10, kt = e / 5120;
    int k = kt * 32 + ((l >> 4) << 3) + j;
    int n = nt * 16 + (l & 15);
    w1f[e] = (k < 200 && n < 150) ? f2bf(W1[k * 150 + n]) : (u16)0;
  }
  u16* w2f = (u16*)(g_wbuf + W2F_OFF);
  for (int e = tid0; e < 17920; e += stride) {
    int j = e & 7, l = (e >> 3) & 63, nt = (e >> 9) % 7, kt = e / 3584;
    int k = kt * 32 + ((l >> 4) << 3) + j;
    int n = nt * 16 + (l & 15);
    w2f[e] = (k < 150 && n < 100) ? f2bf(W2[k * 100 + n]) : (u16)0;
  }
  float* b1p = (float*)(g_wbuf + B1_OFF);
  for (int e = tid0; e < 160; e += stride) b1p[e] = (e < 150) ? b1[e] : 0.f;
  float* b2p = (float*)(g_wbuf + B2_OFF);
  for (int e = tid0; e < 112; e += stride) b2p[e] = (e < 100) ? b2[e] : 0.f;
}

// BM=64, 256 threads (4 waves). Wave (pr,h): pr = wv>>1 owns rows
// 32pr..32pr+31 (m-tiles 2pr,2pr+1); h = wv&1 owns the n-half.
// W streamed through LDS: per kt a 10KB (G1) / 7KB (G2) slice, double-
// buffered, staged via async global_load_lds issued one kt ahead (T3-min:
// STAGE(next) -> compute(cur) -> barrier; vmcnt drained by the barrier).
// B-frags become conflict-free ds_read_b128; W L2 traffic halves (no
// per-wave duplication). x staged as in R7 (swizzled frag LDS).
// LDS 47104 B -> 3 blocks/CU; launch_bounds(256,3) cap 170, no spill.
__global__ __launch_bounds__(256, 3)
void fused_mlp(const float* __restrict__ x, float* __restrict__ out, int B)
{
  __shared__ __align__(16) u16 xs[12800];     // x frags (swizzled) + compact
  __shared__ __align__(16) u16 wbuf[2][5120]; // W slice double-buffer (10KB each)
  __shared__ float ps[2][2][64];              // [phase][half][block row]

  const int tid = threadIdx.x;
  const int lane = tid & 63;
  const int wv = tid >> 6;                  // 0..3
  const int h = wv & 1;
  const int pr = wv >> 1;
  const int cl = lane & 15, gr = lane >> 4;
  const long r0 = (long)blockIdx.x * 64;

  const char* w1g = (const char*)g_wbuf;
  const char* w2g = (const char*)g_wbuf + W2F_OFF;

  // ---- issue W1 slice 0 -> wbuf[0] (async; hides under x staging) ----
  for (int f = wv; f < 10; f += 4)
    gl16(w1g + f * 1024 + lane * 16, (char*)&wbuf[0][0] + f * 1024);

  // ---- stage x tile: coalesced float4 -> packed bf16 -> swizzled LDS ----
  const float* xg = x + r0 * 200;
  #pragma unroll
  for (int i = 0; i < 13; ++i) {
    int c = tid + i * 256;                  // 64 rows * 50 float4-chunks = 3200
    if (c < 3200) {
      int row = c / 50, kc = c % 50;
      float4 v = *reinterpret_cast<const float4*>(xg + row * 200 + kc * 4);
      int k0 = kc * 4;
      int mt = row >> 4;
      int idx;
      if (k0 < 192) {
        int F = mt * 6 + (k0 >> 5);
        int fl = (row & 15) | (((k0 & 31) >> 3) << 4);
        idx = (F * 64 + (fl ^ (F & 7))) * 8 + (k0 & 7);
      } else {                              // k 192..199 -> compact region
        idx = 12288 + mt * 128 + (row & 15) * 8 + (k0 - 192);
      }
      uint2 p;
      p.x = pk2bf(v.x, v.y);
      p.y = pk2bf(v.z, v.w);
      *reinterpret_cast<uint2*>(&xs[idx]) = p;
    }
  }
  __syncthreads();   // (1) xs staged + W1 slice 0 resident (vmcnt drained)

  const int mt0 = pr * 2, mt1 = pr * 2 + 1;
  const f32x4 zz = {0.f, 0.f, 0.f, 0.f};
  f32x4 acc1[2][5];
  #pragma unroll
  for (int i = 0; i < 2; ++i)
    #pragma unroll
    for (int nt = 0; nt < 5; ++nt) acc1[i][nt] = zz;

  // ---- GEMM1: [32 x 224] @ [224 x 80]/wave; W slices via gload_lds ----
  #pragma unroll
  for (int kt = 0; kt < 7; ++kt) {
    // STAGE next slice (kt<6: W1 slice kt+1; kt==6: W2 slice 0) -> other buf
    {
      const char* src = (kt < 6) ? (w1g + (kt + 1) * 10240) : w2g;
      const int nf = (kt < 6) ? 10 : 7;
      char* dst = (char*)&wbuf[(kt + 1) & 1][0];
      for (int f = wv; f < nf; f += 4)
        gl16(src + f * 1024 + lane * 16, dst + f * 1024);
    }
    // A frags from swizzled xs
    bf16x8 a0, a1;
    if (kt < 6) {
      int F0 = mt0 * 6 + kt, F1 = mt1 * 6 + kt;
      a0 = *reinterpret_cast<const bf16x8*>(&xs[(F0 * 64 + (lane ^ (F0 & 7))) * 8]);
      a1 = *reinterpret_cast<const bf16x8*>(&xs[(F1 * 64 + (lane ^ (F1 & 7))) * 8]);
    } else {                                // kt==6: k 192..223, only gr==0 real
      union { bf16x8 v; u32 w[4]; } A0, A1;
      A0.v = *reinterpret_cast<const bf16x8*>(&xs[12288 + mt0 * 128 + cl * 8]);
      A1.v = *reinterpret_cast<const bf16x8*>(&xs[12288 + mt1 * 128 + cl * 8]);
      if (gr != 0) {
        A0.w[0] = A0.w[1] = A0.w[2] = A0.w[3] = 0u;
        A1.w[0] = A1.w[1] = A1.w[2] = A1.w[3] = 0u;
      }
      a0 = A0.v; a1 = A1.v;
    }
    // B frags from current LDS slice (frag nt_global = 5h+nt)
    const u16* wb = &wbuf[kt & 1][0];
    #pragma unroll
    for (int nt = 0; nt < 5; ++nt) {
      bf16x8 b = *reinterpret_cast<const bf16x8*>(&wb[(5 * h + nt) * 512 + lane * 8]);
      acc1[0][nt] = __builtin_amdgcn_mfma_f32_16x16x32_bf16(a0, b, acc1[0][nt], 0, 0, 0);
      acc1[1][nt] = __builtin_amdgcn_mfma_f32_16x16x32_bf16(a1, b, acc1[1][nt], 0, 0, 0);
    }
    __syncthreads();   // reads of buf[kt&1] done; slice kt+1 resident
  }

  // ---- epilogue 1: bias + leaky, out1 partials, h1 -> xs as GEMM2 A-frags ----
  const float* b1p = (const float*)(g_wbuf + B1_OFF);
  float b1v[5];
  #pragma unroll
  for (int nt = 0; nt < 5; ++nt) b1v[nt] = b1p[(5 * h + nt) * 16 + cl];

  float rs0[4] = {0, 0, 0, 0}, rs1[4] = {0, 0, 0, 0};
  #pragma unroll
  for (int nt = 0; nt < 5; ++nt) {
    int k2 = (5 * h + nt) * 16 + cl;        // h1 column = GEMM2 k index
    int kt2 = k2 >> 5;
    int l2base = 16 * ((k2 & 31) >> 3);
    int e2 = k2 & 7;
    #pragma unroll
    for (int j = 0; j < 4; ++j) {
      int l2 = gr * 4 + j + l2base;         // C/D: row=(lane>>4)*4+reg, col=lane&15
      float hv = acc1[0][nt][j] + b1v[nt];
      hv = (hv >= 0.f) ? hv : 0.1f * hv;
      rs0[j] += hv;
      xs[((mt0 * 5 + kt2) * 64 + l2) * 8 + e2] = f2bf(hv);
      float gv = acc1[1][nt][j] + b1v[nt];
      gv = (gv >= 0.f) ? gv : 0.1f * gv;
      rs1[j] += gv;
      xs[((mt1 * 5 + kt2) * 64 + l2) * 8 + e2] = f2bf(gv);
    }
  }
  #pragma unroll
  for (int j = 0; j < 4; ++j) {
    float s0 = rs0[j], s1 = rs1[j];
    #pragma unroll
    for (int mask = 1; mask < 16; mask <<= 1) {
      s0 += __shfl_xor(s0, mask, 64);
      s1 += __shfl_xor(s1, mask, 64);
    }
    if (cl == 0) {
      ps[0][h][mt0 * 16 + gr * 4 + j] = s0;
      ps[0][h][mt1 * 16 + gr * 4 + j] = s1;
    }
  }
  __syncthreads();   // (2) h1 frags + out1 partials visible

  if (tid < 64)
    out[r0 + tid] = (ps[0][0][tid] + ps[0][1][tid]) * (1.f / 150.f);

  // ---- GEMM2: [32 x 160] @ [160 x 64/48]/wave; slices continue parity ----
  // W2 slice s resident in wbuf[(s+1)&1]; iteration kt reads wbuf[(kt+1)&1],
  // stages slice kt+1 into wbuf[kt&1] (its last reads were iteration kt-1).
  f32x4 acc2[2][4];
  #pragma unroll
  for (int i = 0; i < 2; ++i)
    #pragma unroll
    for (int nt = 0; nt < 4; ++nt) acc2[i][nt] = zz;

  #pragma unroll
  for (int kt = 0; kt < 5; ++kt) {
    if (kt < 4) {
      const char* src = w2g + (kt + 1) * 7168;
      char* dst = (char*)&wbuf[kt & 1][0];
      for (int f = wv; f < 7; f += 4)
        gl16(src + f * 1024 + lane * 16, dst + f * 1024);
    }
    bf16x8 a0 = *reinterpret_cast<const bf16x8*>(&xs[((mt0 * 5 + kt) * 64 + lane) * 8]);
    bf16x8 a1 = *reinterpret_cast<const bf16x8*>(&xs[((mt1 * 5 + kt) * 64 + lane) * 8]);
    const u16* wb = &wbuf[(kt + 1) & 1][0];
    #pragma unroll
    for (int nt = 0; nt < 4; ++nt) {
      if (nt < 3 || h == 0) {
        bf16x8 b = *reinterpret_cast<const bf16x8*>(&wb[(4 * h + nt) * 512 + lane * 8]);
        acc2[0][nt] = __builtin_amdgcn_mfma_f32_16x16x32_bf16(a0, b, acc2[0][nt], 0, 0, 0);
        acc2[1][nt] = __builtin_amdgcn_mfma_f32_16x16x32_bf16(a1, b, acc2[1][nt], 0, 0, 0);
      }
    }
    if (kt < 4) __syncthreads();            // publish slice kt+1
  }

  // ---- epilogue 2: bias + leaky, out2 partials ----
  const float* b2p = (const float*)(g_wbuf + B2_OFF);
  float b2v[4];
  #pragma unroll
  for (int nt = 0; nt < 4; ++nt)
    b2v[nt] = (nt < 3 || h == 0) ? b2p[(4 * h + nt) * 16 + cl] : 0.f;

  float t0[4] = {0, 0, 0, 0}, t1[4] = {0, 0, 0, 0};
  #pragma unroll
  for (int nt = 0; nt < 4; ++nt) {
    if (nt < 3 || h == 0) {
      #pragma unroll
      for (int j = 0; j < 4; ++j) {
        float hv = acc2[0][nt][j] + b2v[nt];
        hv = (hv >= 0.f) ? hv : 0.1f * hv;
        t0[j] += hv;
        float gv = acc2[1][nt][j] + b2v[nt];
        gv = (gv >= 0.f) ? gv : 0.1f * gv;
        t1[j] += gv;
      }
    }
  }
  #pragma unroll
  for (int j = 0; j < 4; ++j) {
    float s0 = t0[j], s1 = t1[j];
    #pragma unroll
    for (int mask = 1; mask < 16; mask <<= 1) {
      s0 += __shfl_xor(s0, mask, 64);
      s1 += __shfl_xor(s1, mask, 64);
    }
    if (cl == 0) {
      ps[1][h][mt0 * 16 + gr * 4 + j] = s0;
      ps[1][h][mt1 * 16 + gr * 4 + j] = s1;
    }
  }
  __syncthreads();   // (final) out2 partials visible

  if (tid < 64)
    out[B + r0 + tid] = (ps[1][0][tid] + ps[1][1][tid]) * (1.f / 100.f);
}

extern "C" void kernel_launch(void* const* d_in, const int* in_sizes, int n_in,
                              void* d_out, int out_size, void* d_ws, size_t ws_size,
                              hipStream_t stream)
{
  const float* x  = (const float*)d_in[0];
  const float* W1 = (const float*)d_in[1];
  const float* b1 = (const float*)d_in[2];
  const float* W2 = (const float*)d_in[3];
  const float* b2 = (const float*)d_in[4];
  float* out = (float*)d_out;
  const int B = in_sizes[0] / 200;   // 262144

  prep_kernel<<<64, 256, 0, stream>>>(W1, b1, W2, b2);
  fused_mlp<<<B / 64, 256, 0, stream>>>(x, out, B);
}

// Round 13
// 85.268 us; speedup vs baseline: 1.0704x; 1.0704x over previous
//
#include <hip/hip_runtime.h>

typedef unsigned short u16;
typedef unsigned int u32;
typedef __bf16 bf16x8 __attribute__((ext_vector_type(8)));
typedef float f32x4 __attribute__((ext_vector_type(4)));

// Prepped-weight layout in g_wbuf (bytes), rewritten fully by prep_kernel
// every launch (deterministic):
//   W1f @ 0      : 7kt*10nt*64lane*8elem u16 = 71680 B  (K 200->224, N 150->160, zero-padded)
//   W2f @ 71680  : 5kt*7nt*64lane*8elem u16  = 35840 B  (K 150->160, N 100->112, zero-padded)
//   b1p @ 107520 : 160 f32 (zero-padded)
//   b2p @ 108160 : 112 f32 (zero-padded)
#define W2F_OFF 71680
#define B1_OFF 107520
#define B2_OFF 108160
#define WS_BYTES 108608

__device__ __align__(256) unsigned char g_wbuf[WS_BYTES];

__device__ __forceinline__ u16 f2bf(float f) {
  __bf16 b = (__bf16)f;                    // hw RNE convert
  return __builtin_bit_cast(u16, b);
}
__device__ __forceinline__ u32 pk2bf(float a, float b) {
  return (u32)f2bf(a) | ((u32)f2bf(b) << 16);  // fuses to v_cvt_pk_bf16_f32
}

__global__ void prep_kernel(const float* __restrict__ W1, const float* __restrict__ b1,
                            const float* __restrict__ W2, const float* __restrict__ b2)
{
  const int stride = gridDim.x * blockDim.x;
  const int tid0 = blockIdx.x * blockDim.x + threadIdx.x;
  u16* w1f = (u16*)g_wbuf;
  for (int e = tid0; e < 35840; e += stride) {
    int j = e & 7, l = (e >> 3) & 63, nt = (e >> 9) % 10, kt = e / 5120;
    int k = kt * 32 + ((l >> 4) << 3) + j;
    int n = nt * 16 + (l & 15);
    w1f[e] = (k < 200 && n < 150) ? f2bf(W1[k * 150 + n]) : (u16)0;
  }
  u16* w2f = (u16*)(g_wbuf + W2F_OFF);
  for (int e = tid0; e < 17920; e += stride) {
    int j = e & 7, l = (e >> 3) & 63, nt = (e >> 9) % 7, kt = e / 3584;
    int k = kt * 32 + ((l >> 4) << 3) + j;
    int n = nt * 16 + (l & 15);
    w2f[e] = (k < 150 && n < 100) ? f2bf(W2[k * 100 + n]) : (u16)0;
  }
  float* b1p = (float*)(g_wbuf + B1_OFF);
  for (int e = tid0; e < 160; e += stride) b1p[e] = (e < 150) ? b1[e] : 0.f;
  float* b2p = (float*)(g_wbuf + B2_OFF);
  for (int e = tid0; e < 112; e += stride) b2p[e] = (e < 100) ? b2[e] : 0.f;
}

// BM=64, 512 threads (8 waves). Wave (mt,h): mt = wv>>1 owns ONE 16-row
// m-tile, h = wv&1 owns the n-half. Quarter-size accumulators (acc1 20,
// acc2 16) -> total regs ~88 <= cap 102 at launch_bounds(512,5): spill-free
// WITH full depth-1 B lookahead at >=50% occupancy — the untested cell of
// the occupancy x lookahead matrix. Same R7 skeleton: swizzled x staging,
// 4 barriers, h1 via frag-major LDS. LDS 26624 B.
__global__ __launch_bounds__(512, 5)
void fused_mlp(const float* __restrict__ x, float* __restrict__ out, int B)
{
  __shared__ __align__(16) u16 xs[12800];   // 24576B swizzled frags + 512B compact + pad
  __shared__ float ps[2][2][64];            // [phase][half][block row] partial sums

  const int tid = threadIdx.x;
  const int lane = tid & 63;
  const int wv = tid >> 6;                  // 0..7
  const int h = wv & 1;                     // n-half
  const int mt = wv >> 1;                   // m-tile 0..3
  const int cl = lane & 15, gr = lane >> 4;
  const long r0 = (long)blockIdx.x * 64;

  const u16* w1g = (const u16*)g_wbuf;
  const u16* w2g = (const u16*)(g_wbuf + W2F_OFF);

  // ---- stage x tile: coalesced float4 -> packed bf16 -> swizzled LDS ----
  const float* xg = x + r0 * 200;
  #pragma unroll
  for (int i = 0; i < 7; ++i) {
    int c = tid + i * 512;                  // 64 rows * 50 float4-chunks = 3200
    if (c < 3200) {
      int row = c / 50, kc = c % 50;
      float4 v = *reinterpret_cast<const float4*>(xg + row * 200 + kc * 4);
      int k0 = kc * 4;
      int m = row >> 4;
      int idx;
      if (k0 < 192) {
        int F = m * 6 + (k0 >> 5);
        int fl = (row & 15) | (((k0 & 31) >> 3) << 4);
        idx = (F * 64 + (fl ^ (F & 7))) * 8 + (k0 & 7);
      } else {                              // k 192..199 -> compact region
        idx = 12288 + m * 128 + (row & 15) * 8 + (k0 - 192);
      }
      uint2 p;
      p.x = pk2bf(v.x, v.y);
      p.y = pk2bf(v.z, v.w);
      *reinterpret_cast<uint2*>(&xs[idx]) = p;
    }
  }

  // preload kt=0 B-frags (no xs dependency -> overlaps staging)
  bf16x8 bfr[5];
  #pragma unroll
  for (int nt = 0; nt < 5; ++nt)
    bfr[nt] = *reinterpret_cast<const bf16x8*>(w1g + ((0 * 10 + 5 * h + nt) * 64 + lane) * 8);

  __syncthreads();   // (1) xs fully staged

  const f32x4 zz = {0.f, 0.f, 0.f, 0.f};
  f32x4 acc1[5];
  #pragma unroll
  for (int nt = 0; nt < 5; ++nt) acc1[nt] = zz;

  // ---- GEMM1: [16 x 224] @ [224 x 80] per wave, depth-1 B lookahead ----
  #pragma unroll
  for (int kt = 0; kt < 7; ++kt) {
    bf16x8 bnx[5];
    if (kt < 6) {
      #pragma unroll
      for (int nt = 0; nt < 5; ++nt)
        bnx[nt] = *reinterpret_cast<const bf16x8*>(w1g + (((kt + 1) * 10 + 5 * h + nt) * 64 + lane) * 8);
    }
    bf16x8 a;
    if (kt < 6) {
      int F = mt * 6 + kt;
      a = *reinterpret_cast<const bf16x8*>(&xs[(F * 64 + (lane ^ (F & 7))) * 8]);
    } else {                                // kt==6: k 192..223, only gr==0 real
      union { bf16x8 v; u32 w[4]; } A;
      A.v = *reinterpret_cast<const bf16x8*>(&xs[12288 + mt * 128 + cl * 8]);
      if (gr != 0) { A.w[0] = A.w[1] = A.w[2] = A.w[3] = 0u; }
      a = A.v;
    }
    #pragma unroll
    for (int nt = 0; nt < 5; ++nt)
      acc1[nt] = __builtin_amdgcn_mfma_f32_16x16x32_bf16(a, bfr[nt], acc1[nt], 0, 0, 0);
    if (kt < 6) {
      #pragma unroll
      for (int nt = 0; nt < 5; ++nt) bfr[nt] = bnx[nt];
    }
  }
  __syncthreads();   // (2) all GEMM1 A-reads done before h1 overwrites xs

  // ---- epilogue 1: bias + leaky, out1 partials, h1 -> xs as GEMM2 A-frags ----
  const float* b1p = (const float*)(g_wbuf + B1_OFF);
  float b1v[5];
  #pragma unroll
  for (int nt = 0; nt < 5; ++nt) b1v[nt] = b1p[(5 * h + nt) * 16 + cl];

  float rs[4] = {0, 0, 0, 0};
  #pragma unroll
  for (int nt = 0; nt < 5; ++nt) {
    int k2 = (5 * h + nt) * 16 + cl;        // h1 column = GEMM2 k index
    int kt2 = k2 >> 5;
    int l2base = 16 * ((k2 & 31) >> 3);
    int e2 = k2 & 7;
    #pragma unroll
    for (int j = 0; j < 4; ++j) {
      int l2 = gr * 4 + j + l2base;         // C/D: row=(lane>>4)*4+reg, col=lane&15
      float hv = acc1[nt][j] + b1v[nt];
      hv = (hv >= 0.f) ? hv : 0.1f * hv;
      rs[j] += hv;
      xs[((mt * 5 + kt2) * 64 + l2) * 8 + e2] = f2bf(hv);
    }
  }
  #pragma unroll
  for (int j = 0; j < 4; ++j) {
    float s = rs[j];
    #pragma unroll
    for (int mask = 1; mask < 16; mask <<= 1) s += __shfl_xor(s, mask, 64);
    if (cl == 0) ps[0][h][mt * 16 + gr * 4 + j] = s;
  }
  __syncthreads();   // (3) h1 frags + out1 partials visible

  if (tid < 64)
    out[r0 + tid] = (ps[0][0][tid] + ps[0][1][tid]) * (1.f / 150.f);

  // ---- GEMM2: [16 x 160] @ [160 x 64/48] per wave; inline B loads ----
  f32x4 acc2[4];
  #pragma unroll
  for (int nt = 0; nt < 4; ++nt) acc2[nt] = zz;

  #pragma unroll
  for (int kt = 0; kt < 5; ++kt) {
    bf16x8 a = *reinterpret_cast<const bf16x8*>(&xs[((mt * 5 + kt) * 64 + lane) * 8]);
    #pragma unroll
    for (int nt = 0; nt < 4; ++nt) {
      if (nt < 3 || h == 0) {
        bf16x8 b = *reinterpret_cast<const bf16x8*>(w2g + ((kt * 7 + 4 * h + nt) * 64 + lane) * 8);
        acc2[nt] = __builtin_amdgcn_mfma_f32_16x16x32_bf16(a, b, acc2[nt], 0, 0, 0);
      }
    }
  }

  // ---- epilogue 2: bias + leaky, out2 partials ----
  const float* b2p = (const float*)(g_wbuf + B2_OFF);
  float b2v[4];
  #pragma unroll
  for (int nt = 0; nt < 4; ++nt)
    b2v[nt] = (nt < 3 || h == 0) ? b2p[(4 * h + nt) * 16 + cl] : 0.f;

  float ts[4] = {0, 0, 0, 0};
  #pragma unroll
  for (int nt = 0; nt < 4; ++nt) {
    if (nt < 3 || h == 0) {
      #pragma unroll
      for (int j = 0; j < 4; ++j) {
        float hv = acc2[nt][j] + b2v[nt];
        hv = (hv >= 0.f) ? hv : 0.1f * hv;
        ts[j] += hv;
      }
    }
  }
  #pragma unroll
  for (int j = 0; j < 4; ++j) {
    float s = ts[j];
    #pragma unroll
    for (int mask = 1; mask < 16; mask <<= 1) s += __shfl_xor(s, mask, 64);
    if (cl == 0) ps[1][h][mt * 16 + gr * 4 + j] = s;
  }
  __syncthreads();   // (4) out2 partials visible

  if (tid < 64)
    out[B + r0 + tid] = (ps[1][0][tid] + ps[1][1][tid]) * (1.f / 100.f);
}

extern "C" void kernel_launch(void* const* d_in, const int* in_sizes, int n_in,
                              void* d_out, int out_size, void* d_ws, size_t ws_size,
                              hipStream_t stream)
{
  const float* x  = (const float*)d_in[0];
  const float* W1 = (const float*)d_in[1];
  const float* b1 = (const float*)d_in[2];
  const float* W2 = (const float*)d_in[3];
  const float* b2 = (const float*)d_in[4];
  float* out = (float*)d_out;
  const int B = in_sizes[0] / 200;   // 262144

  prep_kernel<<<64, 256, 0, stream>>>(W1, b1, W2, b2);
  fused_mlp<<<B / 64, 512, 0, stream>>>(x, out, B);
}

// Round 14
// 75.962 us; speedup vs baseline: 1.2015x; 1.1225x over previous
//
#include <hip/hip_runtime.h>

typedef unsigned short u16;
typedef unsigned int u32;
typedef __bf16 bf16x8 __attribute__((ext_vector_type(8)));
typedef float f32x4 __attribute__((ext_vector_type(4)));

// Prepped-weight layout in g_wbuf (bytes), rewritten fully by prep_kernel
// every launch (deterministic):
//   W1f @ 0      : 7kt*10nt*64lane*8elem u16 = 71680 B  (K 200->224, N 150->160, zero-padded)
//   W2f @ 71680  : 5kt*7nt*64lane*8elem u16  = 35840 B  (K 150->160, N 100->112, zero-padded)
//   b1p @ 107520 : 160 f32 (zero-padded)
//   b2p @ 108160 : 112 f32 (zero-padded)
#define W2F_OFF 71680
#define B1_OFF 107520
#define B2_OFF 108160
#define WS_BYTES 108608

__device__ __align__(256) unsigned char g_wbuf[WS_BYTES];

__device__ __forceinline__ u16 f2bf(float f) {
  __bf16 b = (__bf16)f;                    // hw RNE convert
  return __builtin_bit_cast(u16, b);
}
__device__ __forceinline__ u32 pk2bf(float a, float b) {
  return (u32)f2bf(a) | ((u32)f2bf(b) << 16);  // fuses to v_cvt_pk_bf16_f32
}

__global__ void prep_kernel(const float* __restrict__ W1, const float* __restrict__ b1,
                            const float* __restrict__ W2, const float* __restrict__ b2)
{
  const int stride = gridDim.x * blockDim.x;
  const int tid0 = blockIdx.x * blockDim.x + threadIdx.x;
  u16* w1f = (u16*)g_wbuf;
  for (int e = tid0; e < 35840; e += stride) {
    int j = e & 7, l = (e >> 3) & 63, nt = (e >> 9) % 10, kt = e / 5120;
    int k = kt * 32 + ((l >> 4) << 3) + j;
    int n = nt * 16 + (l & 15);
    w1f[e] = (k < 200 && n < 150) ? f2bf(W1[k * 150 + n]) : (u16)0;
  }
  u16* w2f = (u16*)(g_wbuf + W2F_OFF);
  for (int e = tid0; e < 17920; e += stride) {
    int j = e & 7, l = (e >> 3) & 63, nt = (e >> 9) % 7, kt = e / 3584;
    int k = kt * 32 + ((l >> 4) << 3) + j;
    int n = nt * 16 + (l & 15);
    w2f[e] = (k < 150 && n < 100) ? f2bf(W2[k * 100 + n]) : (u16)0;
  }
  float* b1p = (float*)(g_wbuf + B1_OFF);
  for (int e = tid0; e < 160; e += stride) b1p[e] = (e < 150) ? b1[e] : 0.f;
  float* b2p = (float*)(g_wbuf + B2_OFF);
  for (int e = tid0; e < 112; e += stride) b2p[e] = (e < 100) ? b2[e] : 0.f;
}

// BM=128, 512 threads (8 waves) — R7's proven per-wave shape (2 m-tiles x
// n-half, depth-1 B lookahead, 4-barrier loose schedule) doubled in rows:
// wave (pr,h): pr = wv>>1 (0..3) owns rows 32pr..32pr+31 (m-tiles 2pr,2pr+1),
// h = wv&1 owns the n-half. Halves per-row W L2 traffic (same-CU duplicate
// B-loads become L1 hits) and per-row staging/barrier overhead vs R7.
// x-fragment LDS slots XOR-swizzled by frag id (slot = fl ^ (F&7)).
// LDS 53248 B -> 3 blocks/CU; launch_bounds(512,4) cap 128 (R7-verified fit).
__global__ __launch_bounds__(512, 4)
void fused_mlp(const float* __restrict__ x, float* __restrict__ out, int B)
{
  __shared__ __align__(16) u16 xs[25600];   // 49152B swizzled frags + 2048B compact
  __shared__ float ps[2][2][128];           // [phase][half][block row] partial sums

  const int tid = threadIdx.x;
  const int lane = tid & 63;
  const int wv = tid >> 6;                  // 0..7
  const int h = wv & 1;                     // n-half
  const int pr = wv >> 1;                   // row pair 0..3
  const int cl = lane & 15, gr = lane >> 4;
  const long r0 = (long)blockIdx.x * 128;

  const u16* w1g = (const u16*)g_wbuf;
  const u16* w2g = (const u16*)(g_wbuf + W2F_OFF);

  // ---- stage x tile: coalesced float4 -> packed bf16 -> swizzled LDS ----
  const float* xg = x + r0 * 200;
  #pragma unroll
  for (int i = 0; i < 13; ++i) {
    int c = tid + i * 512;                  // 128 rows * 50 float4-chunks = 6400
    if (c < 6400) {
      int row = c / 50, kc = c % 50;
      float4 v = *reinterpret_cast<const float4*>(xg + row * 200 + kc * 4);
      int k0 = kc * 4;
      int mt = row >> 4;                    // 0..7
      int idx;
      if (k0 < 192) {
        int F = mt * 6 + (k0 >> 5);         // 0..47
        int fl = (row & 15) | (((k0 & 31) >> 3) << 4);
        idx = (F * 64 + (fl ^ (F & 7))) * 8 + (k0 & 7);
      } else {                              // k 192..199 -> compact region
        idx = 24576 + mt * 128 + (row & 15) * 8 + (k0 - 192);
      }
      uint2 p;
      p.x = pk2bf(v.x, v.y);
      p.y = pk2bf(v.z, v.w);
      *reinterpret_cast<uint2*>(&xs[idx]) = p;
    }
  }

  // preload kt=0 B-frags (no xs dependency -> overlaps staging)
  bf16x8 bfr[5];
  #pragma unroll
  for (int nt = 0; nt < 5; ++nt)
    bfr[nt] = *reinterpret_cast<const bf16x8*>(w1g + ((0 * 10 + 5 * h + nt) * 64 + lane) * 8);

  __syncthreads();   // (1) xs fully staged

  const int mt0 = pr * 2, mt1 = pr * 2 + 1;
  const f32x4 zz = {0.f, 0.f, 0.f, 0.f};
  f32x4 acc1[2][5];
  #pragma unroll
  for (int i = 0; i < 2; ++i)
    #pragma unroll
    for (int nt = 0; nt < 5; ++nt) acc1[i][nt] = zz;

  // ---- GEMM1: [32 x 224] @ [224 x 80] per wave, depth-1 B lookahead ----
  #pragma unroll
  for (int kt = 0; kt < 7; ++kt) {
    bf16x8 bnx[5];
    if (kt < 6) {
      #pragma unroll
      for (int nt = 0; nt < 5; ++nt)
        bnx[nt] = *reinterpret_cast<const bf16x8*>(w1g + (((kt + 1) * 10 + 5 * h + nt) * 64 + lane) * 8);
    }
    bf16x8 a0, a1;
    if (kt < 6) {
      int F0 = mt0 * 6 + kt, F1 = mt1 * 6 + kt;
      a0 = *reinterpret_cast<const bf16x8*>(&xs[(F0 * 64 + (lane ^ (F0 & 7))) * 8]);
      a1 = *reinterpret_cast<const bf16x8*>(&xs[(F1 * 64 + (lane ^ (F1 & 7))) * 8]);
    } else {                                // kt==6: k 192..223, only gr==0 real
      union { bf16x8 v; u32 w[4]; } A0, A1;
      A0.v = *reinterpret_cast<const bf16x8*>(&xs[24576 + mt0 * 128 + cl * 8]);
      A1.v = *reinterpret_cast<const bf16x8*>(&xs[24576 + mt1 * 128 + cl * 8]);
      if (gr != 0) {
        A0.w[0] = A0.w[1] = A0.w[2] = A0.w[3] = 0u;
        A1.w[0] = A1.w[1] = A1.w[2] = A1.w[3] = 0u;
      }
      a0 = A0.v; a1 = A1.v;
    }
    #pragma unroll
    for (int nt = 0; nt < 5; ++nt) {
      acc1[0][nt] = __builtin_amdgcn_mfma_f32_16x16x32_bf16(a0, bfr[nt], acc1[0][nt], 0, 0, 0);
      acc1[1][nt] = __builtin_amdgcn_mfma_f32_16x16x32_bf16(a1, bfr[nt], acc1[1][nt], 0, 0, 0);
    }
    if (kt < 6) {
      #pragma unroll
      for (int nt = 0; nt < 5; ++nt) bfr[nt] = bnx[nt];
    }
  }
  __syncthreads();   // (2) all GEMM1 A-reads done before h1 overwrites xs

  // ---- epilogue 1: bias + leaky, out1 partials, h1 -> xs as GEMM2 A-frags ----
  const float* b1p = (const float*)(g_wbuf + B1_OFF);
  float b1v[5];
  #pragma unroll
  for (int nt = 0; nt < 5; ++nt) b1v[nt] = b1p[(5 * h + nt) * 16 + cl];

  float rs0[4] = {0, 0, 0, 0}, rs1[4] = {0, 0, 0, 0};
  #pragma unroll
  for (int nt = 0; nt < 5; ++nt) {
    int k2 = (5 * h + nt) * 16 + cl;        // h1 column = GEMM2 k index
    int kt2 = k2 >> 5;
    int l2base = 16 * ((k2 & 31) >> 3);
    int e2 = k2 & 7;
    #pragma unroll
    for (int j = 0; j < 4; ++j) {
      int l2 = gr * 4 + j + l2base;         // C/D: row=(lane>>4)*4+reg, col=lane&15
      float hv = acc1[0][nt][j] + b1v[nt];
      hv = (hv >= 0.f) ? hv : 0.1f * hv;
      rs0[j] += hv;
      xs[((mt0 * 5 + kt2) * 64 + l2) * 8 + e2] = f2bf(hv);
      float gv = acc1[1][nt][j] + b1v[nt];
      gv = (gv >= 0.f) ? gv : 0.1f * gv;
      rs1[j] += gv;
      xs[((mt1 * 5 + kt2) * 64 + l2) * 8 + e2] = f2bf(gv);
    }
  }
  #pragma unroll
  for (int j = 0; j < 4; ++j) {
    float s0 = rs0[j], s1 = rs1[j];
    #pragma unroll
    for (int mask = 1; mask < 16; mask <<= 1) {
      s0 += __shfl_xor(s0, mask, 64);
      s1 += __shfl_xor(s1, mask, 64);
    }
    if (cl == 0) {
      ps[0][h][mt0 * 16 + gr * 4 + j] = s0;
      ps[0][h][mt1 * 16 + gr * 4 + j] = s1;
    }
  }
  __syncthreads();   // (3) h1 frags + out1 partials visible

  if (tid < 128)     // finalize out1 (128 rows)
    out[r0 + tid] = (ps[0][0][tid] + ps[0][1][tid]) * (1.f / 150.f);

  // ---- GEMM2: [32 x 160] @ [160 x 64/48] per wave, depth-1 B lookahead ----
  f32x4 acc2[2][4];
  #pragma unroll
  for (int i = 0; i < 2; ++i)
    #pragma unroll
    for (int nt = 0; nt < 4; ++nt) acc2[i][nt] = zz;

  bf16x8 b2r[4];
  #pragma unroll
  for (int nt = 0; nt < 4; ++nt)
    if (nt < 3 || h == 0)
      b2r[nt] = *reinterpret_cast<const bf16x8*>(w2g + ((0 * 7 + 4 * h + nt) * 64 + lane) * 8);

  #pragma unroll
  for (int kt = 0; kt < 5; ++kt) {
    bf16x8 bnx2[4];
    if (kt < 4) {
      #pragma unroll
      for (int nt = 0; nt < 4; ++nt)
        if (nt < 3 || h == 0)
          bnx2[nt] = *reinterpret_cast<const bf16x8*>(w2g + (((kt + 1) * 7 + 4 * h + nt) * 64 + lane) * 8);
    }
    bf16x8 a0 = *reinterpret_cast<const bf16x8*>(&xs[((mt0 * 5 + kt) * 64 + lane) * 8]);
    bf16x8 a1 = *reinterpret_cast<const bf16x8*>(&xs[((mt1 * 5 + kt) * 64 + lane) * 8]);
    #pragma unroll
    for (int nt = 0; nt < 4; ++nt) {
      if (nt < 3 || h == 0) {
        acc2[0][nt] = __builtin_amdgcn_mfma_f32_16x16x32_bf16(a0, b2r[nt], acc2[0][nt], 0, 0, 0);
        acc2[1][nt] = __builtin_amdgcn_mfma_f32_16x16x32_bf16(a1, b2r[nt], acc2[1][nt], 0, 0, 0);
      }
    }
    if (kt < 4) {
      #pragma unroll
      for (int nt = 0; nt < 4; ++nt)
        if (nt < 3 || h == 0) b2r[nt] = bnx2[nt];
    }
  }

  // ---- epilogue 2: bias + leaky, out2 partials ----
  const float* b2p = (const float*)(g_wbuf + B2_OFF);
  float b2v[4];
  #pragma unroll
  for (int nt = 0; nt < 4; ++nt)
    b2v[nt] = (nt < 3 || h == 0) ? b2p[(4 * h + nt) * 16 + cl] : 0.f;

  float t0[4] = {0, 0, 0, 0}, t1[4] = {0, 0, 0, 0};
  #pragma unroll
  for (int nt = 0; nt < 4; ++nt) {
    if (nt < 3 || h == 0) {
      #pragma unroll
      for (int j = 0; j < 4; ++j) {
        float hv = acc2[0][nt][j] + b2v[nt];
        hv = (hv >= 0.f) ? hv : 0.1f * hv;
        t0[j] += hv;
        float gv = acc2[1][nt][j] + b2v[nt];
        gv = (gv >= 0.f) ? gv : 0.1f * gv;
        t1[j] += gv;
      }
    }
  }
  #pragma unroll
  for (int j = 0; j < 4; ++j) {
    float s0 = t0[j], s1 = t1[j];
    #pragma unroll
    for (int mask = 1; mask < 16; mask <<= 1) {
      s0 += __shfl_xor(s0, mask, 64);
      s1 += __shfl_xor(s1, mask, 64);
    }
    if (cl == 0) {
      ps[1][h][mt0 * 16 + gr * 4 + j] = s0;
      ps[1][h][mt1 * 16 + gr * 4 + j] = s1;
    }
  }
  __syncthreads();   // (4) out2 partials visible

  if (tid < 128)
    out[B + r0 + tid] = (ps[1][0][tid] + ps[1][1][tid]) * (1.f / 100.f);
}

extern "C" void kernel_launch(void* const* d_in, const int* in_sizes, int n_in,
                              void* d_out, int out_size, void* d_ws, size_t ws_size,
                              hipStream_t stream)
{
  const float* x  = (const float*)d_in[0];
  const float* W1 = (const float*)d_in[1];
  const float* b1 = (const float*)d_in[2];
  const float* W2 = (const float*)d_in[3];
  const float* b2 = (const float*)d_in[4];
  float* out = (float*)d_out;
  const int B = in_sizes[0] / 200;   // 262144

  prep_kernel<<<64, 256, 0, stream>>>(W1, b1, W2, b2);
  fused_mlp<<<B / 128, 512, 0, stream>>>(x, out, B);
}